// Round 19
// baseline (5624.337 us; speedup 1.0000x reference)
//
#include <hip/hip_runtime.h>
#include <math.h>

// ===================== INSTRUMENTATION ROUND =====================
// Real R16 pipeline (best, 32.85us) runs first and produces d_out.
// Then rep-looped profiling clones of its 3 kernels (scratch outputs)
// so each gets its own rocprof top-5 row.
// =================================================================

constexpr int Bn = 1024;
constexpr int S  = 512;
constexpr int H  = 768;
constexpr int D1 = 128;
constexpr int HV = H / 4;     // 192 float4 per feature row
constexpr int NH = 512;       // cls-head blocks (first in launch-1 grid)

constexpr int POOL_REPS = 96;
constexpr int CLS_REPS  = 320;
constexpr int CRC_REPS  = 384;

__device__ __forceinline__ int opaque_zero() {
  int zero;
  asm volatile("v_mov_b32 %0, 0" : "=v"(zero));
  return zero;
}

// ---------------- REAL KERNELS (R16-exact) ----------------

__global__ __launch_bounds__(256) void fused_pool_clshead(
    const float* __restrict__ feat, const int* __restrict__ start,
    const int* __restrict__ endp, float* __restrict__ gp,
    const float* __restrict__ W1, float* __restrict__ P) {
  __shared__ __align__(16) char smem[12288];

  const int t = threadIdx.x;

  if (blockIdx.x < NH) {
    float (*g)[384] = reinterpret_cast<float (*)[384]>(smem);
    float (*part)[4][D1] = reinterpret_cast<float (*)[4][D1]>(smem + 6144);

    const int c = blockIdx.x & 1;
    const int e0 = (blockIdx.x >> 1) * 4;
    const int dglob0 = c * 384;

    for (int i = t; i < 384; i += 256) {
      const int e = i / 96;
      const int j = i % 96;
      float4 v = *reinterpret_cast<const float4*>(
          feat + (size_t)(e0 + e) * S * H + dglob0 + j * 4);
      reinterpret_cast<float4*>(&g[e][0])[j] = v;
    }
    __syncthreads();

    const int k = t & (D1 - 1);
    const int sub = t >> 7;
    const int gofs = sub * 192;
    const float* Wc = W1 + (size_t)(dglob0 + gofs) * D1 + k;

    float a0 = 0.f, a1 = 0.f, a2 = 0.f, a3 = 0.f;
    #pragma unroll 4
    for (int d = 0; d < 192; d += 4) {
      float w0 = Wc[(size_t)(d + 0) * D1];
      float w1 = Wc[(size_t)(d + 1) * D1];
      float w2 = Wc[(size_t)(d + 2) * D1];
      float w3 = Wc[(size_t)(d + 3) * D1];
      float4 g0 = *reinterpret_cast<const float4*>(&g[0][gofs + d]);
      float4 g1 = *reinterpret_cast<const float4*>(&g[1][gofs + d]);
      float4 g2 = *reinterpret_cast<const float4*>(&g[2][gofs + d]);
      float4 g3 = *reinterpret_cast<const float4*>(&g[3][gofs + d]);
      a0 += g0.x * w0 + g0.y * w1 + g0.z * w2 + g0.w * w3;
      a1 += g1.x * w0 + g1.y * w1 + g1.z * w2 + g1.w * w3;
      a2 += g2.x * w0 + g2.y * w1 + g2.z * w2 + g2.w * w3;
      a3 += g3.x * w0 + g3.y * w1 + g3.z * w2 + g3.w * w3;
    }
    part[sub][0][k] = a0;
    part[sub][1][k] = a1;
    part[sub][2][k] = a2;
    part[sub][3][k] = a3;
    __syncthreads();

    if (t < D1) {
      #pragma unroll
      for (int e = 0; e < 4; ++e) {
        P[((size_t)c * Bn + (e0 + e)) * D1 + t] = part[0][e][t] + part[1][e][t];
      }
    }
    return;
  }

  {
    float4 (*pacc)[3][64] = reinterpret_cast<float4 (*)[3][64]>(smem);
    const int b = blockIdx.x - NH;
    const int w = t >> 6;
    const int l = t & 63;
    const float4* base =
        reinterpret_cast<const float4*>(feat) + (size_t)b * (S * HV);

    const int s0 = start[b];
    const int s1 = endp[b];

    float4 c0{0,0,0,0}, c1{0,0,0,0}, c2{0,0,0,0};
    float4 d0{0,0,0,0}, d1{0,0,0,0}, d2{0,0,0,0};
    int s = s0 + w;
    for (; s + 4 < s1; s += 8) {
      const float4* r0 = base + (size_t)s * HV;
      const float4* r1 = base + (size_t)(s + 4) * HV;
      float4 u0 = r0[l], u1 = r0[l + 64], u2 = r0[l + 128];
      float4 v0 = r1[l], v1 = r1[l + 64], v2 = r1[l + 128];
      c0.x += u0.x; c0.y += u0.y; c0.z += u0.z; c0.w += u0.w;
      c1.x += u1.x; c1.y += u1.y; c1.z += u1.z; c1.w += u1.w;
      c2.x += u2.x; c2.y += u2.y; c2.z += u2.z; c2.w += u2.w;
      d0.x += v0.x; d0.y += v0.y; d0.z += v0.z; d0.w += v0.w;
      d1.x += v1.x; d1.y += v1.y; d1.z += v1.z; d1.w += v1.w;
      d2.x += v2.x; d2.y += v2.y; d2.z += v2.z; d2.w += v2.w;
    }
    for (; s < s1; s += 4) {
      const float4* r0 = base + (size_t)s * HV;
      float4 u0 = r0[l], u1 = r0[l + 64], u2 = r0[l + 128];
      c0.x += u0.x; c0.y += u0.y; c0.z += u0.z; c0.w += u0.w;
      c1.x += u1.x; c1.y += u1.y; c1.z += u1.z; c1.w += u1.w;
      c2.x += u2.x; c2.y += u2.y; c2.z += u2.z; c2.w += u2.w;
    }
    c0.x += d0.x; c0.y += d0.y; c0.z += d0.z; c0.w += d0.w;
    c1.x += d1.x; c1.y += d1.y; c1.z += d1.z; c1.w += d1.w;
    c2.x += d2.x; c2.y += d2.y; c2.z += d2.z; c2.w += d2.w;
    pacc[w][0][l] = c0;
    pacc[w][1][l] = c1;
    pacc[w][2][l] = c2;
    __syncthreads();

    if (t < 192) {
      const int seg = t >> 6, ln = t & 63;
      float4 a = pacc[0][seg][ln], bb = pacc[1][seg][ln];
      float4 cq = pacc[2][seg][ln], dq = pacc[3][seg][ln];
      const float inv = 1.0f / (float)(s1 - s0);
      float4 r;
      r.x = ((a.x + bb.x) + (cq.x + dq.x)) * inv;
      r.y = ((a.y + bb.y) + (cq.y + dq.y)) * inv;
      r.z = ((a.z + bb.z) + (cq.z + dq.z)) * inv;
      r.w = ((a.w + bb.w) + (cq.w + dq.w)) * inv;
      reinterpret_cast<float4*>(gp)[(size_t)b * HV + t] = r;
    }
  }
}

__global__ __launch_bounds__(256) void crc_head(
    const float* __restrict__ gp, const float* __restrict__ W1,
    float* __restrict__ P) {
  __shared__ float g[4][192];
  __shared__ float part[2][4][D1];

  const int t = threadIdx.x;
  const int cc = blockIdx.x & 3;
  const int e0 = (blockIdx.x >> 2) * 4;
  const int dd04 = cc * 48;

  if (t < 192) {
    const int e = t / 48;
    const int j = t % 48;
    float4 v = reinterpret_cast<const float4*>(gp)[(size_t)(e0 + e) * HV + dd04 + j];
    reinterpret_cast<float4*>(&g[e][0])[j] = v;
  }
  __syncthreads();

  const int k = t & (D1 - 1);
  const int sub = t >> 7;
  const int gofs = sub * 96;
  const float* Wc = W1 + (size_t)(H + cc * 192 + gofs) * D1 + k;

  float a0 = 0.f, a1 = 0.f, a2 = 0.f, a3 = 0.f;
  #pragma unroll 2
  for (int d = 0; d < 96; d += 8) {
    float w0 = Wc[(size_t)(d + 0) * D1];
    float w1 = Wc[(size_t)(d + 1) * D1];
    float w2 = Wc[(size_t)(d + 2) * D1];
    float w3 = Wc[(size_t)(d + 3) * D1];
    float w4 = Wc[(size_t)(d + 4) * D1];
    float w5 = Wc[(size_t)(d + 5) * D1];
    float w6 = Wc[(size_t)(d + 6) * D1];
    float w7 = Wc[(size_t)(d + 7) * D1];
    #define ACC8(i)                                                        \
    {                                                                      \
      float4 gA = *reinterpret_cast<const float4*>(&g[i][gofs + d]);       \
      float4 gB = *reinterpret_cast<const float4*>(&g[i][gofs + d + 4]);   \
      a##i += gA.x * w0 + gA.y * w1 + gA.z * w2 + gA.w * w3                \
            + gB.x * w4 + gB.y * w5 + gB.z * w6 + gB.w * w7;               \
    }
    ACC8(0) ACC8(1) ACC8(2) ACC8(3)
    #undef ACC8
  }
  part[sub][0][k] = a0;
  part[sub][1][k] = a1;
  part[sub][2][k] = a2;
  part[sub][3][k] = a3;
  __syncthreads();

  if (t < D1) {
    #pragma unroll
    for (int e = 0; e < 4; ++e) {
      P[((size_t)(2 + cc) * Bn + (e0 + e)) * D1 + t] =
          part[0][e][t] + part[1][e][t];
    }
  }
}

__global__ __launch_bounds__(256) void finalize(
    const float* __restrict__ P, const float* __restrict__ b1,
    const float* __restrict__ W2, const float* __restrict__ b2,
    float* __restrict__ out) {
  const int t = threadIdx.x;
  const int w = t >> 6, l = t & 63;
  const int e = blockIdx.x * 4 + w;
  const int k0 = l, k1 = l + 64;
  float h0 = b1[k0], h1 = b1[k1];
  #pragma unroll
  for (int c = 0; c < 6; ++c) {
    h0 += P[((size_t)c * Bn + e) * D1 + k0];
    h1 += P[((size_t)c * Bn + e) * D1 + k1];
  }
  h0 = fmaxf(h0, 0.f); h1 = fmaxf(h1, 0.f);
  float v = h0 * W2[k0] + h1 * W2[k1];
  #pragma unroll
  for (int off = 32; off > 0; off >>= 1) v += __shfl_down(v, off);
  if (l == 0) out[e] = 1.0f / (1.0f + expf(-(v + b2[0])));
}

// ---------------- PROFILING CLONES (scratch outputs) ----------------

// Pool alone, grid 1024, rotating window (defeats L3 warmth across reps).
__global__ __launch_bounds__(256) void pool_prof(
    const float* __restrict__ feat, const int* __restrict__ start,
    const int* __restrict__ endp, float* __restrict__ gp2) {
  __shared__ float4 pacc[4][3][64];
  const int t = threadIdx.x;
  const int b = blockIdx.x;
  const int w = t >> 6;
  const int l = t & 63;
  const int zero = opaque_zero();
  const float4* base =
      reinterpret_cast<const float4*>(feat) + (size_t)b * (S * HV) + zero;

  const int s0 = start[b];
  const int s1 = endp[b];
  const int len = s1 - s0;
  const float inv = 1.0f / (float)len;

  for (int rep = 0; rep < POOL_REPS; ++rep) {
    const int x = (rep == POOL_REPS - 1) ? s0 : (1 + ((s0 - 1) + rep * 37) % 199);
    const int e = x + len;
    float4 c0{0,0,0,0}, c1{0,0,0,0}, c2{0,0,0,0};
    float4 d0{0,0,0,0}, d1{0,0,0,0}, d2{0,0,0,0};
    int s = x + w;
    for (; s + 4 < e; s += 8) {
      const float4* r0 = base + (size_t)s * HV;
      const float4* r1 = base + (size_t)(s + 4) * HV;
      float4 u0 = r0[l], u1 = r0[l + 64], u2 = r0[l + 128];
      float4 v0 = r1[l], v1 = r1[l + 64], v2 = r1[l + 128];
      c0.x += u0.x; c0.y += u0.y; c0.z += u0.z; c0.w += u0.w;
      c1.x += u1.x; c1.y += u1.y; c1.z += u1.z; c1.w += u1.w;
      c2.x += u2.x; c2.y += u2.y; c2.z += u2.z; c2.w += u2.w;
      d0.x += v0.x; d0.y += v0.y; d0.z += v0.z; d0.w += v0.w;
      d1.x += v1.x; d1.y += v1.y; d1.z += v1.z; d1.w += v1.w;
      d2.x += v2.x; d2.y += v2.y; d2.z += v2.z; d2.w += v2.w;
    }
    for (; s < e; s += 4) {
      const float4* r0 = base + (size_t)s * HV;
      float4 u0 = r0[l], u1 = r0[l + 64], u2 = r0[l + 128];
      c0.x += u0.x; c0.y += u0.y; c0.z += u0.z; c0.w += u0.w;
      c1.x += u1.x; c1.y += u1.y; c1.z += u1.z; c1.w += u1.w;
      c2.x += u2.x; c2.y += u2.y; c2.z += u2.z; c2.w += u2.w;
    }
    c0.x += d0.x; c0.y += d0.y; c0.z += d0.z; c0.w += d0.w;
    c1.x += d1.x; c1.y += d1.y; c1.z += d1.z; c1.w += d1.w;
    c2.x += d2.x; c2.y += d2.y; c2.z += d2.z; c2.w += d2.w;
    pacc[w][0][l] = c0;
    pacc[w][1][l] = c1;
    pacc[w][2][l] = c2;
    __syncthreads();

    if (t < 192) {
      const int seg = t >> 6, ln = t & 63;
      float4 a = pacc[0][seg][ln], bb = pacc[1][seg][ln];
      float4 cq = pacc[2][seg][ln], dq = pacc[3][seg][ln];
      float4 r;
      r.x = ((a.x + bb.x) + (cq.x + dq.x)) * inv;
      r.y = ((a.y + bb.y) + (cq.y + dq.y)) * inv;
      r.z = ((a.z + bb.z) + (cq.z + dq.z)) * inv;
      r.w = ((a.w + bb.w) + (cq.w + dq.w)) * inv;
      reinterpret_cast<float4*>(gp2)[(size_t)b * HV + t] = r;
    }
    __syncthreads();
  }
}

// CLS head alone, grid 512.
__global__ __launch_bounds__(256) void cls_prof(
    const float* __restrict__ feat, const float* __restrict__ W1,
    float* __restrict__ P2) {
  __shared__ float g[4][384];
  __shared__ float part[2][4][D1];

  const int t = threadIdx.x;
  const int c = blockIdx.x & 1;
  const int e0 = (blockIdx.x >> 1) * 4;
  const int dglob0 = c * 384;
  const int zero = opaque_zero();
  const float* featz = feat + zero;
  const float* W1z = W1 + zero;

  for (int rep = 0; rep < CLS_REPS; ++rep) {
    for (int i = t; i < 384; i += 256) {
      const int e = i / 96;
      const int j = i % 96;
      float4 v = *reinterpret_cast<const float4*>(
          featz + (size_t)(e0 + e) * S * H + dglob0 + j * 4);
      reinterpret_cast<float4*>(&g[e][0])[j] = v;
    }
    __syncthreads();

    const int k = t & (D1 - 1);
    const int sub = t >> 7;
    const int gofs = sub * 192;
    const float* Wc = W1z + (size_t)(dglob0 + gofs) * D1 + k;

    float a0 = 0.f, a1 = 0.f, a2 = 0.f, a3 = 0.f;
    #pragma unroll 4
    for (int d = 0; d < 192; d += 4) {
      float w0 = Wc[(size_t)(d + 0) * D1];
      float w1 = Wc[(size_t)(d + 1) * D1];
      float w2 = Wc[(size_t)(d + 2) * D1];
      float w3 = Wc[(size_t)(d + 3) * D1];
      float4 g0 = *reinterpret_cast<const float4*>(&g[0][gofs + d]);
      float4 g1 = *reinterpret_cast<const float4*>(&g[1][gofs + d]);
      float4 g2 = *reinterpret_cast<const float4*>(&g[2][gofs + d]);
      float4 g3 = *reinterpret_cast<const float4*>(&g[3][gofs + d]);
      a0 += g0.x * w0 + g0.y * w1 + g0.z * w2 + g0.w * w3;
      a1 += g1.x * w0 + g1.y * w1 + g1.z * w2 + g1.w * w3;
      a2 += g2.x * w0 + g2.y * w1 + g2.z * w2 + g2.w * w3;
      a3 += g3.x * w0 + g3.y * w1 + g3.z * w2 + g3.w * w3;
    }
    part[sub][0][k] = a0;
    part[sub][1][k] = a1;
    part[sub][2][k] = a2;
    part[sub][3][k] = a3;
    __syncthreads();

    if (t < D1) {
      #pragma unroll
      for (int e = 0; e < 4; ++e) {
        P2[((size_t)c * Bn + (e0 + e)) * D1 + t] = part[0][e][t] + part[1][e][t];
      }
    }
    __syncthreads();
  }
}

// CRC head alone, grid 1024 (reads real gp — launched after real pipeline).
__global__ __launch_bounds__(256) void crc_prof(
    const float* __restrict__ gp, const float* __restrict__ W1,
    float* __restrict__ P2) {
  __shared__ float g[4][192];
  __shared__ float part[2][4][D1];

  const int t = threadIdx.x;
  const int cc = blockIdx.x & 3;
  const int e0 = (blockIdx.x >> 2) * 4;
  const int dd04 = cc * 48;
  const int zero = opaque_zero();
  const float* gpz = gp + zero;
  const float* W1z = W1 + zero;

  for (int rep = 0; rep < CRC_REPS; ++rep) {
    if (t < 192) {
      const int e = t / 48;
      const int j = t % 48;
      float4 v =
          reinterpret_cast<const float4*>(gpz)[(size_t)(e0 + e) * HV + dd04 + j];
      reinterpret_cast<float4*>(&g[e][0])[j] = v;
    }
    __syncthreads();

    const int k = t & (D1 - 1);
    const int sub = t >> 7;
    const int gofs = sub * 96;
    const float* Wc = W1z + (size_t)(H + cc * 192 + gofs) * D1 + k;

    float a0 = 0.f, a1 = 0.f, a2 = 0.f, a3 = 0.f;
    #pragma unroll 2
    for (int d = 0; d < 96; d += 8) {
      float w0 = Wc[(size_t)(d + 0) * D1];
      float w1 = Wc[(size_t)(d + 1) * D1];
      float w2 = Wc[(size_t)(d + 2) * D1];
      float w3 = Wc[(size_t)(d + 3) * D1];
      float w4 = Wc[(size_t)(d + 4) * D1];
      float w5 = Wc[(size_t)(d + 5) * D1];
      float w6 = Wc[(size_t)(d + 6) * D1];
      float w7 = Wc[(size_t)(d + 7) * D1];
      #define ACC8(i)                                                      \
      {                                                                    \
        float4 gA = *reinterpret_cast<const float4*>(&g[i][gofs + d]);     \
        float4 gB = *reinterpret_cast<const float4*>(&g[i][gofs + d + 4]); \
        a##i += gA.x * w0 + gA.y * w1 + gA.z * w2 + gA.w * w3              \
              + gB.x * w4 + gB.y * w5 + gB.z * w6 + gB.w * w7;             \
      }
      ACC8(0) ACC8(1) ACC8(2) ACC8(3)
      #undef ACC8
    }
    part[sub][0][k] = a0;
    part[sub][1][k] = a1;
    part[sub][2][k] = a2;
    part[sub][3][k] = a3;
    __syncthreads();

    if (t < D1) {
      #pragma unroll
      for (int e = 0; e < 4; ++e) {
        P2[((size_t)(2 + cc) * Bn + (e0 + e)) * D1 + t] =
            part[0][e][t] + part[1][e][t];
      }
    }
    __syncthreads();
  }
}

extern "C" void kernel_launch(void* const* d_in, const int* in_sizes, int n_in,
                              void* d_out, int out_size, void* d_ws, size_t ws_size,
                              hipStream_t stream) {
  const float* feat = (const float*)d_in[0];
  const int* start  = (const int*)d_in[1];
  const int* endp   = (const int*)d_in[2];
  const float* W1   = (const float*)d_in[3];
  const float* b1   = (const float*)d_in[4];
  const float* W2   = (const float*)d_in[5];
  const float* b2   = (const float*)d_in[6];
  float* out = (float*)d_out;

  float* wsf = (float*)d_ws;
  float* gp  = wsf;                            // [Bn][768]
  float* P   = gp + (size_t)Bn * H;            // [6][Bn][D1]
  float* gp2 = P + (size_t)6 * Bn * D1;        // scratch [Bn][768]
  float* P2  = gp2 + (size_t)Bn * H;           // scratch [6][Bn][D1]

  // Real R16 pipeline (produces d_out):
  hipLaunchKernelGGL(fused_pool_clshead, dim3(NH + Bn), dim3(256), 0,
                     stream, feat, start, endp, gp, W1, P);
  hipLaunchKernelGGL(crc_head, dim3(Bn), dim3(256), 0, stream, gp, W1, P);
  hipLaunchKernelGGL(finalize, dim3(Bn / 4), dim3(256), 0, stream,
                     P, b1, W2, b2, out);

  // Profiling clones (scratch outputs):
  hipLaunchKernelGGL(pool_prof, dim3(Bn), dim3(256), 0, stream,
                     feat, start, endp, gp2);
  hipLaunchKernelGGL(cls_prof, dim3(NH), dim3(256), 0, stream,
                     feat, W1, P2);
  hipLaunchKernelGGL(crc_prof, dim3(Bn), dim3(256), 0, stream,
                     gp, W1, P2);
}

// Round 20
// 43.711 us; speedup vs baseline: 128.6707x; 128.6707x over previous
//
#include <hip/hip_runtime.h>
#include <math.h>

// Problem constants (from reference):
constexpr int Bn = 1024;
constexpr int S  = 512;
constexpr int H  = 768;
constexpr int D1 = 128;
constexpr int HV = H / 4;     // 192 float4 per feature row
constexpr int K2 = 2 * H;     // 1536
constexpr int NCAST = 16;     // W1T cast blocks (first in launch-1 grid)

typedef _Float16 half8 __attribute__((ext_vector_type(8)));
typedef _Float16 half4v __attribute__((ext_vector_type(4)));
typedef float floatx4 __attribute__((ext_vector_type(4)));

// ws layout:
//   g16 [1024][1536] _Float16 — concat [cls | span-mean], 3 MB
//   w1t [128][1536]  _Float16 — W1 transposed+cast, 384 KB

// Launch 1: blocks [0,NCAST) cast W1 -> w1t; [NCAST, NCAST+1024) pool.
// Pool block (R16-exact body): 4 waves x stride-4 rows, lane owns 3 float4
// cols, 6 loads in flight, LDS cross-wave reduce. Adds: CLS row -> f16 first
// half of g16; mean -> f16 second half.
__global__ __launch_bounds__(256) void pool_cast(
    const float* __restrict__ feat, const int* __restrict__ start,
    const int* __restrict__ endp, const float* __restrict__ W1,
    _Float16* __restrict__ g16, _Float16* __restrict__ w1t) {
  __shared__ float4 pacc[4][3][64];   // 12 KB (pool path only)
  const int t = threadIdx.x;

  if (blockIdx.x < NCAST) {
    // ---- cast W1[1536][128] -> w1t[128][1536] (f16) ----
    const int c = blockIdx.x;
    const int n = t & 127;
    const int sb = t >> 7;            // 0/1
    #pragma unroll
    for (int j = 0; j < 6; ++j) {
      const int k0 = c * 96 + sb * 48 + j * 8;
      _Float16 h[8];
      #pragma unroll
      for (int i = 0; i < 8; ++i) {
        h[i] = (_Float16)W1[(size_t)(k0 + i) * D1 + n];  // coalesced per row
      }
      *reinterpret_cast<half8*>(w1t + (size_t)n * K2 + k0) =
          *reinterpret_cast<half8*>(h);
    }
    return;
  }

  // ---- pool (R16-exact) + f16 writes ----
  const int b = blockIdx.x - NCAST;
  const int w = t >> 6;
  const int l = t & 63;
  const float4* base =
      reinterpret_cast<const float4*>(feat) + (size_t)b * (S * HV);

  // CLS row -> g16 first half (independent of span; loads issue early)
  if (t < 192) {
    float4 cv = base[t];              // row 0, col t
    half4v hc;
    hc.x = (_Float16)cv.x; hc.y = (_Float16)cv.y;
    hc.z = (_Float16)cv.z; hc.w = (_Float16)cv.w;
    *reinterpret_cast<half4v*>(g16 + (size_t)b * K2 + t * 4) = hc;
  }

  const int s0 = start[b];
  const int s1 = endp[b];

  float4 c0{0,0,0,0}, c1{0,0,0,0}, c2{0,0,0,0};
  float4 d0{0,0,0,0}, d1{0,0,0,0}, d2{0,0,0,0};
  int s = s0 + w;
  for (; s + 4 < s1; s += 8) {
    const float4* r0 = base + (size_t)s * HV;
    const float4* r1 = base + (size_t)(s + 4) * HV;
    float4 u0 = r0[l], u1 = r0[l + 64], u2 = r0[l + 128];
    float4 v0 = r1[l], v1 = r1[l + 64], v2 = r1[l + 128];
    c0.x += u0.x; c0.y += u0.y; c0.z += u0.z; c0.w += u0.w;
    c1.x += u1.x; c1.y += u1.y; c1.z += u1.z; c1.w += u1.w;
    c2.x += u2.x; c2.y += u2.y; c2.z += u2.z; c2.w += u2.w;
    d0.x += v0.x; d0.y += v0.y; d0.z += v0.z; d0.w += v0.w;
    d1.x += v1.x; d1.y += v1.y; d1.z += v1.z; d1.w += v1.w;
    d2.x += v2.x; d2.y += v2.y; d2.z += v2.z; d2.w += v2.w;
  }
  for (; s < s1; s += 4) {
    const float4* r0 = base + (size_t)s * HV;
    float4 u0 = r0[l], u1 = r0[l + 64], u2 = r0[l + 128];
    c0.x += u0.x; c0.y += u0.y; c0.z += u0.z; c0.w += u0.w;
    c1.x += u1.x; c1.y += u1.y; c1.z += u1.z; c1.w += u1.w;
    c2.x += u2.x; c2.y += u2.y; c2.z += u2.z; c2.w += u2.w;
  }
  c0.x += d0.x; c0.y += d0.y; c0.z += d0.z; c0.w += d0.w;
  c1.x += d1.x; c1.y += d1.y; c1.z += d1.z; c1.w += d1.w;
  c2.x += d2.x; c2.y += d2.y; c2.z += d2.z; c2.w += d2.w;
  pacc[w][0][l] = c0;
  pacc[w][1][l] = c1;
  pacc[w][2][l] = c2;
  __syncthreads();

  if (t < 192) {
    const int seg = t >> 6, ln = t & 63;
    float4 a = pacc[0][seg][ln], bb = pacc[1][seg][ln];
    float4 cq = pacc[2][seg][ln], dq = pacc[3][seg][ln];
    const float inv = 1.0f / (float)(s1 - s0);
    half4v r;
    r.x = (_Float16)((((a.x + bb.x) + (cq.x + dq.x))) * inv);
    r.y = (_Float16)((((a.y + bb.y) + (cq.y + dq.y))) * inv);
    r.z = (_Float16)((((a.z + bb.z) + (cq.z + dq.z))) * inv);
    r.w = (_Float16)((((a.w + bb.w) + (cq.w + dq.w))) * inv);
    *reinterpret_cast<half4v*>(g16 + (size_t)b * K2 + H + t * 4) = r;
  }
}

// Launch 2: MFMA head + fused finalize.
// Block = 16 examples, 256 thr (4 waves). Wave w owns N-tiles {w*32, w*32+16}.
// D = G(16x1536,f16) x W1T^T(1536x128,f16), fp32 accum.
// A/B fragments use the SAME k-index function (k0 + (l>>4)*8 + e) so any
// internal MFMA k-permutation cancels. C/D: col=lane&15, row=(lane>>4)*4+reg
// (HW-verified). Epilogue: +b1, relu, *W2, shfl-reduce over n, sigmoid.
__global__ __launch_bounds__(256) void head_mfma(
    const _Float16* __restrict__ g16, const _Float16* __restrict__ w1t,
    const float* __restrict__ b1, const float* __restrict__ W2,
    const float* __restrict__ b2, float* __restrict__ out) {
  __shared__ float part[4][16];

  const int t = threadIdx.x;
  const int w = t >> 6;
  const int l = t & 63;
  const int e0 = blockIdx.x * 16;
  const int lg = l >> 4;            // k-group 0..3
  const int li = l & 15;            // A-row / B-col

  const half8* Ap = reinterpret_cast<const half8*>(
      g16 + (size_t)(e0 + li) * K2 + lg * 8);
  const int n0 = w * 32 + li;
  const int n1 = n0 + 16;
  const half8* Bp0 = reinterpret_cast<const half8*>(
      w1t + (size_t)n0 * K2 + lg * 8);
  const half8* Bp1 = reinterpret_cast<const half8*>(
      w1t + (size_t)n1 * K2 + lg * 8);

  floatx4 acc0 = {0.f, 0.f, 0.f, 0.f};
  floatx4 acc1 = {0.f, 0.f, 0.f, 0.f};
  #pragma unroll 4
  for (int kk = 0; kk < K2 / 32; ++kk) {    // 48 K-steps of 32
    half8 a   = Ap[kk * 4];                 // G[e0+li][kk*32 + lg*8 + 0..7]
    half8 bb0 = Bp0[kk * 4];                // W1T[n0][same k's]
    half8 bb1 = Bp1[kk * 4];
    acc0 = __builtin_amdgcn_mfma_f32_16x16x32_f16(a, bb0, acc0, 0, 0, 0);
    acc1 = __builtin_amdgcn_mfma_f32_16x16x32_f16(a, bb1, acc1, 0, 0, 0);
  }

  // Epilogue: lane holds cols n0,n1 for rows m = lg*4 + r.
  const float b1a = b1[n0], b1b = b1[n1];
  const float w2a = W2[n0], w2b = W2[n1];
  float sr[4];
  #pragma unroll
  for (int r = 0; r < 4; ++r) {
    float h0 = fmaxf(acc0[r] + b1a, 0.f) * w2a;
    float h1 = fmaxf(acc1[r] + b1b, 0.f) * w2b;
    float v = h0 + h1;
    v += __shfl_xor(v, 1);
    v += __shfl_xor(v, 2);
    v += __shfl_xor(v, 4);
    v += __shfl_xor(v, 8);
    sr[r] = v;                       // valid on li==0 lanes
  }
  if (li == 0) {
    #pragma unroll
    for (int r = 0; r < 4; ++r) part[w][lg * 4 + r] = sr[r];
  }
  __syncthreads();

  if (t < 16) {
    float hsum = part[0][t] + part[1][t] + part[2][t] + part[3][t] + b2[0];
    out[e0 + t] = 1.0f / (1.0f + expf(-hsum));
  }
}

extern "C" void kernel_launch(void* const* d_in, const int* in_sizes, int n_in,
                              void* d_out, int out_size, void* d_ws, size_t ws_size,
                              hipStream_t stream) {
  const float* feat = (const float*)d_in[0];   // [B,S,H] fp32
  const int* start  = (const int*)d_in[1];     // [B]
  const int* endp   = (const int*)d_in[2];     // [B]
  const float* W1   = (const float*)d_in[3];   // [2H,D1]
  const float* b1   = (const float*)d_in[4];   // [D1]
  const float* W2   = (const float*)d_in[5];   // [D1,1]
  const float* b2   = (const float*)d_in[6];   // [1]
  float* out = (float*)d_out;                  // [B]

  _Float16* g16 = (_Float16*)d_ws;             // [1024][1536]
  _Float16* w1t = g16 + (size_t)Bn * K2;       // [128][1536]

  hipLaunchKernelGGL(pool_cast, dim3(NCAST + Bn), dim3(256), 0, stream,
                     feat, start, endp, W1, g16, w1t);
  hipLaunchKernelGGL(head_mfma, dim3(Bn / 16), dim3(256), 0, stream,
                     g16, w1t, b1, W2, b2, out);
}

// Round 21
// 34.305 us; speedup vs baseline: 163.9524x; 1.2742x over previous
//
#include <hip/hip_runtime.h>
#include <math.h>

// Problem constants (from reference):
constexpr int Bn = 1024;
constexpr int S  = 512;
constexpr int H  = 768;
constexpr int D1 = 128;
constexpr int HV = H / 4;     // 192 float4 per feature row
constexpr int K2 = 2 * H;     // 1536
constexpr int NK = K2 / 32;   // 48 K-steps
constexpr int NCAST = 16;     // W1 cast blocks (first in launch-1 grid)

typedef _Float16 half8 __attribute__((ext_vector_type(8)));
typedef float floatx4 __attribute__((ext_vector_type(4)));

// ws layout:
//   gs  [64][48][64][8]  f16 — G in MFMA fragment order (3 MB)
//   w1s [8][48][64][8]   f16 — W1^T in MFMA fragment order (384 KB)
//   ts  [1024][8]        f32 — per-(example, n-tile) partial sums (32 KB)
//
// Fragment order: element (lane=lg*16+idx, e) of k-tile kk holds k = kk*32 +
// lg*8 + e. A-side idx = example-within-tile; B-side idx = n-within-tile.
// A and B use the SAME (lane,e)->k map, so any internal MFMA k-permutation
// cancels (validated R20: absmax 3.9e-3 = f16 rounding).

__device__ __forceinline__ size_t swz_off(int tile, int kk, int lg, int idx) {
  return ((((size_t)tile * NK + kk) * 64) + lg * 16 + idx) * 8;
}

// Launch 1: blocks [0,NCAST): cast W1 -> w1s; [NCAST,+1024): R16-exact pool
// writing swizzled f16 (cls half + mean half).
__global__ __launch_bounds__(256) void pool_cast(
    const float* __restrict__ feat, const int* __restrict__ start,
    const int* __restrict__ endp, const float* __restrict__ W1,
    _Float16* __restrict__ gs, _Float16* __restrict__ w1s) {
  __shared__ float4 pacc[4][3][64];   // 12 KB (pool path only)
  const int t = threadIdx.x;

  if (blockIdx.x < NCAST) {
    // ---- cast W1[1536][128] -> w1s (B fragment order) ----
    const int c  = blockIdx.x;
    const int n  = t & 127;
    const int sb = t >> 7;            // 0/1
    const int nt = n >> 4, ni = n & 15;
    #pragma unroll
    for (int j = 0; j < 6; ++j) {
      const int k0 = c * 96 + sb * 48 + j * 8;   // 8-aligned
      _Float16 h[8];
      #pragma unroll
      for (int i = 0; i < 8; ++i) {
        h[i] = (_Float16)W1[(size_t)(k0 + i) * D1 + n];  // coalesced per row
      }
      const int kk = k0 >> 5, lg = (k0 >> 3) & 3;
      *reinterpret_cast<half8*>(w1s + swz_off(nt, kk, lg, ni)) =
          *reinterpret_cast<half8*>(h);
    }
    return;
  }

  // ---- pool (R16-exact) + swizzled f16 writes ----
  const int b = blockIdx.x - NCAST;
  const int eg = b >> 4, li = b & 15;
  const int w = t >> 6;
  const int l = t & 63;
  const float4* base =
      reinterpret_cast<const float4*>(feat) + (size_t)b * (S * HV);

  // CLS row -> k in [0,768)
  if (t < 192) {
    float4 cv = base[t];              // row 0, col t (k = 4t)
    const int k = t * 4;
    const int kk = k >> 5, lg = (k >> 3) & 3, e = k & 7;
    _Float16* dst = gs + swz_off(eg, kk, lg, li) + e;
    dst[0] = (_Float16)cv.x; dst[1] = (_Float16)cv.y;
    dst[2] = (_Float16)cv.z; dst[3] = (_Float16)cv.w;
  }

  const int s0 = start[b];
  const int s1 = endp[b];

  float4 c0{0,0,0,0}, c1{0,0,0,0}, c2{0,0,0,0};
  float4 d0{0,0,0,0}, d1{0,0,0,0}, d2{0,0,0,0};
  int s = s0 + w;
  for (; s + 4 < s1; s += 8) {
    const float4* r0 = base + (size_t)s * HV;
    const float4* r1 = base + (size_t)(s + 4) * HV;
    float4 u0 = r0[l], u1 = r0[l + 64], u2 = r0[l + 128];
    float4 v0 = r1[l], v1 = r1[l + 64], v2 = r1[l + 128];
    c0.x += u0.x; c0.y += u0.y; c0.z += u0.z; c0.w += u0.w;
    c1.x += u1.x; c1.y += u1.y; c1.z += u1.z; c1.w += u1.w;
    c2.x += u2.x; c2.y += u2.y; c2.z += u2.z; c2.w += u2.w;
    d0.x += v0.x; d0.y += v0.y; d0.z += v0.z; d0.w += v0.w;
    d1.x += v1.x; d1.y += v1.y; d1.z += v1.z; d1.w += v1.w;
    d2.x += v2.x; d2.y += v2.y; d2.z += v2.z; d2.w += v2.w;
  }
  for (; s < s1; s += 4) {
    const float4* r0 = base + (size_t)s * HV;
    float4 u0 = r0[l], u1 = r0[l + 64], u2 = r0[l + 128];
    c0.x += u0.x; c0.y += u0.y; c0.z += u0.z; c0.w += u0.w;
    c1.x += u1.x; c1.y += u1.y; c1.z += u1.z; c1.w += u1.w;
    c2.x += u2.x; c2.y += u2.y; c2.z += u2.z; c2.w += u2.w;
  }
  c0.x += d0.x; c0.y += d0.y; c0.z += d0.z; c0.w += d0.w;
  c1.x += d1.x; c1.y += d1.y; c1.z += d1.z; c1.w += d1.w;
  c2.x += d2.x; c2.y += d2.y; c2.z += d2.z; c2.w += d2.w;
  pacc[w][0][l] = c0;
  pacc[w][1][l] = c1;
  pacc[w][2][l] = c2;
  __syncthreads();

  if (t < 192) {
    const int seg = t >> 6, ln = t & 63;
    float4 a = pacc[0][seg][ln], bb = pacc[1][seg][ln];
    float4 cq = pacc[2][seg][ln], dq = pacc[3][seg][ln];
    const float inv = 1.0f / (float)(s1 - s0);
    const int k = H + t * 4;          // crc half: k in [768,1536)
    const int kk = k >> 5, lg = (k >> 3) & 3, e = k & 7;
    _Float16* dst = gs + swz_off(eg, kk, lg, li) + e;
    dst[0] = (_Float16)(((a.x + bb.x) + (cq.x + dq.x)) * inv);
    dst[1] = (_Float16)(((a.y + bb.y) + (cq.y + dq.y)) * inv);
    dst[2] = (_Float16)(((a.z + bb.z) + (cq.z + dq.z)) * inv);
    dst[3] = (_Float16)(((a.w + bb.w) + (cq.w + dq.w)) * inv);
  }
}

// Launch 2: MFMA head. Grid 512 x 64 thr; wave = one 16x16 tile (eg, nt).
// A/B loads are wave-contiguous 1 KB (fragment-order layout). 2-chain K ILP.
// Epilogue: +b1, relu, *W2, butterfly over 16 cols -> ts[e][nt].
__global__ __launch_bounds__(64) void head_mfma(
    const _Float16* __restrict__ gs, const _Float16* __restrict__ w1s,
    const float* __restrict__ b1, const float* __restrict__ W2,
    float* __restrict__ ts) {
  const int l  = threadIdx.x;
  const int eg = blockIdx.x >> 3;
  const int nt = blockIdx.x & 7;

  const half8* Ap = reinterpret_cast<const half8*>(gs) + (size_t)eg * NK * 64 + l;
  const half8* Bp = reinterpret_cast<const half8*>(w1s) + (size_t)nt * NK * 64 + l;

  floatx4 acc0 = {0.f, 0.f, 0.f, 0.f};
  floatx4 acc1 = {0.f, 0.f, 0.f, 0.f};
  #pragma unroll 8
  for (int kk = 0; kk < NK; kk += 2) {
    half8 a0 = Ap[(size_t)kk * 64];
    half8 b0 = Bp[(size_t)kk * 64];
    half8 a1 = Ap[(size_t)(kk + 1) * 64];
    half8 b1v = Bp[(size_t)(kk + 1) * 64];
    acc0 = __builtin_amdgcn_mfma_f32_16x16x32_f16(a0, b0, acc0, 0, 0, 0);
    acc1 = __builtin_amdgcn_mfma_f32_16x16x32_f16(a1, b1v, acc1, 0, 0, 0);
  }

  // C/D: col = l&15 (n-local), row = (l>>4)*4 + r (example-local). [m89]
  const int col = l & 15;
  const int n = nt * 16 + col;
  const float b1n = b1[n];
  const float w2n = W2[n];
  #pragma unroll
  for (int r = 0; r < 4; ++r) {
    float h = fmaxf((acc0[r] + acc1[r]) + b1n, 0.f) * w2n;
    h += __shfl_xor(h, 1);
    h += __shfl_xor(h, 2);
    h += __shfl_xor(h, 4);
    h += __shfl_xor(h, 8);
    if (col == 0) {
      const int m = (l >> 4) * 4 + r;
      ts[(size_t)(eg * 16 + m) * 8 + nt] = h;
    }
  }
}

// Launch 3: out[e] = sigmoid(b2 + sum_nt ts[e][nt]). 1024 threads.
__global__ __launch_bounds__(256) void fin(
    const float* __restrict__ ts, const float* __restrict__ b2,
    float* __restrict__ out) {
  const int e = blockIdx.x * 256 + threadIdx.x;
  const float4* p = reinterpret_cast<const float4*>(ts + (size_t)e * 8);
  float4 u = p[0], v = p[1];
  float s = ((u.x + u.y) + (u.z + u.w)) + ((v.x + v.y) + (v.z + v.w)) + b2[0];
  out[e] = 1.0f / (1.0f + expf(-s));
}

extern "C" void kernel_launch(void* const* d_in, const int* in_sizes, int n_in,
                              void* d_out, int out_size, void* d_ws, size_t ws_size,
                              hipStream_t stream) {
  const float* feat = (const float*)d_in[0];   // [B,S,H] fp32
  const int* start  = (const int*)d_in[1];     // [B]
  const int* endp   = (const int*)d_in[2];     // [B]
  const float* W1   = (const float*)d_in[3];   // [2H,D1]
  const float* b1   = (const float*)d_in[4];   // [D1]
  const float* W2   = (const float*)d_in[5];   // [D1,1]
  const float* b2   = (const float*)d_in[6];   // [1]
  float* out = (float*)d_out;                  // [B]

  _Float16* gs  = (_Float16*)d_ws;             // [64][48][64][8]
  _Float16* w1s = gs + (size_t)Bn * K2;        // [8][48][64][8]
  float* ts     = (float*)(w1s + (size_t)D1 * K2);  // [1024][8]

  hipLaunchKernelGGL(pool_cast, dim3(NCAST + Bn), dim3(256), 0, stream,
                     feat, start, endp, W1, gs, w1s);
  hipLaunchKernelGGL(head_mfma, dim3(512), dim3(64), 0, stream,
                     gs, w1s, b1, W2, ts);
  hipLaunchKernelGGL(fin, dim3(Bn / 256), dim3(256), 0, stream,
                     ts, b2, out);
}

// Round 22
// 33.703 us; speedup vs baseline: 166.8798x; 1.0179x over previous
//
#include <hip/hip_runtime.h>
#include <math.h>

// Problem constants (from reference):
constexpr int Bn = 1024;
constexpr int S  = 512;
constexpr int H  = 768;
constexpr int D1 = 128;
constexpr int HV = H / 4;     // 192 float4 per feature row
constexpr int K2 = 2 * H;     // 1536
constexpr int NK = K2 / 32;   // 48 K-steps
constexpr int NCAST = 16;     // W1 cast blocks (first in launch-1 grid)

typedef _Float16 half8 __attribute__((ext_vector_type(8)));
typedef float floatx4 __attribute__((ext_vector_type(4)));

// ws layout:
//   gs  [64][48][64][8]  f16 — G in MFMA fragment order (3 MB)
//   w1s [8][48][64][8]   f16 — W1^T in MFMA fragment order (384 KB)
//   ts  [1024][8]        f32 — per-(example, n-tile) partial sums (32 KB)
//
// Fragment order: element (lane=lg*16+idx, e) of k-tile kk holds k = kk*32 +
// lg*8 + e. A and B use the SAME (lane,e)->k map, so any internal MFMA
// k-permutation cancels (validated R20/R21: absmax 3.9e-3 = f16 rounding).

__device__ __forceinline__ size_t swz_off(int tile, int kk, int lg, int idx) {
  return ((((size_t)tile * NK + kk) * 64) + lg * 16 + idx) * 8;
}

// Launch 1 (R21-exact): blocks [0,NCAST): cast W1 -> w1s; [NCAST,+1024):
// R16-exact pool writing swizzled f16 (cls half + mean half).
__global__ __launch_bounds__(256) void pool_cast(
    const float* __restrict__ feat, const int* __restrict__ start,
    const int* __restrict__ endp, const float* __restrict__ W1,
    _Float16* __restrict__ gs, _Float16* __restrict__ w1s) {
  __shared__ float4 pacc[4][3][64];   // 12 KB (pool path only)
  const int t = threadIdx.x;

  if (blockIdx.x < NCAST) {
    const int c  = blockIdx.x;
    const int n  = t & 127;
    const int sb = t >> 7;            // 0/1
    const int nt = n >> 4, ni = n & 15;
    #pragma unroll
    for (int j = 0; j < 6; ++j) {
      const int k0 = c * 96 + sb * 48 + j * 8;   // 8-aligned
      _Float16 h[8];
      #pragma unroll
      for (int i = 0; i < 8; ++i) {
        h[i] = (_Float16)W1[(size_t)(k0 + i) * D1 + n];  // coalesced per row
      }
      const int kk = k0 >> 5, lg = (k0 >> 3) & 3;
      *reinterpret_cast<half8*>(w1s + swz_off(nt, kk, lg, ni)) =
          *reinterpret_cast<half8*>(h);
    }
    return;
  }

  // ---- pool (R16-exact) + swizzled f16 writes ----
  const int b = blockIdx.x - NCAST;
  const int eg = b >> 4, li = b & 15;
  const int w = t >> 6;
  const int l = t & 63;
  const float4* base =
      reinterpret_cast<const float4*>(feat) + (size_t)b * (S * HV);

  // CLS row -> k in [0,768)
  if (t < 192) {
    float4 cv = base[t];              // row 0, col t (k = 4t)
    const int k = t * 4;
    const int kk = k >> 5, lg = (k >> 3) & 3, e = k & 7;
    _Float16* dst = gs + swz_off(eg, kk, lg, li) + e;
    dst[0] = (_Float16)cv.x; dst[1] = (_Float16)cv.y;
    dst[2] = (_Float16)cv.z; dst[3] = (_Float16)cv.w;
  }

  const int s0 = start[b];
  const int s1 = endp[b];

  float4 c0{0,0,0,0}, c1{0,0,0,0}, c2{0,0,0,0};
  float4 d0{0,0,0,0}, d1{0,0,0,0}, d2{0,0,0,0};
  int s = s0 + w;
  for (; s + 4 < s1; s += 8) {
    const float4* r0 = base + (size_t)s * HV;
    const float4* r1 = base + (size_t)(s + 4) * HV;
    float4 u0 = r0[l], u1 = r0[l + 64], u2 = r0[l + 128];
    float4 v0 = r1[l], v1 = r1[l + 64], v2 = r1[l + 128];
    c0.x += u0.x; c0.y += u0.y; c0.z += u0.z; c0.w += u0.w;
    c1.x += u1.x; c1.y += u1.y; c1.z += u1.z; c1.w += u1.w;
    c2.x += u2.x; c2.y += u2.y; c2.z += u2.z; c2.w += u2.w;
    d0.x += v0.x; d0.y += v0.y; d0.z += v0.z; d0.w += v0.w;
    d1.x += v1.x; d1.y += v1.y; d1.z += v1.z; d1.w += v1.w;
    d2.x += v2.x; d2.y += v2.y; d2.z += v2.z; d2.w += v2.w;
  }
  for (; s < s1; s += 4) {
    const float4* r0 = base + (size_t)s * HV;
    float4 u0 = r0[l], u1 = r0[l + 64], u2 = r0[l + 128];
    c0.x += u0.x; c0.y += u0.y; c0.z += u0.z; c0.w += u0.w;
    c1.x += u1.x; c1.y += u1.y; c1.z += u1.z; c1.w += u1.w;
    c2.x += u2.x; c2.y += u2.y; c2.z += u2.z; c2.w += u2.w;
  }
  c0.x += d0.x; c0.y += d0.y; c0.z += d0.z; c0.w += d0.w;
  c1.x += d1.x; c1.y += d1.y; c1.z += d1.z; c1.w += d1.w;
  c2.x += d2.x; c2.y += d2.y; c2.z += d2.z; c2.w += d2.w;
  pacc[w][0][l] = c0;
  pacc[w][1][l] = c1;
  pacc[w][2][l] = c2;
  __syncthreads();

  if (t < 192) {
    const int seg = t >> 6, ln = t & 63;
    float4 a = pacc[0][seg][ln], bb = pacc[1][seg][ln];
    float4 cq = pacc[2][seg][ln], dq = pacc[3][seg][ln];
    const float inv = 1.0f / (float)(s1 - s0);
    const int k = H + t * 4;          // crc half: k in [768,1536)
    const int kk = k >> 5, lg = (k >> 3) & 3, e = k & 7;
    _Float16* dst = gs + swz_off(eg, kk, lg, li) + e;
    dst[0] = (_Float16)(((a.x + bb.x) + (cq.x + dq.x)) * inv);
    dst[1] = (_Float16)(((a.y + bb.y) + (cq.y + dq.y)) * inv);
    dst[2] = (_Float16)(((a.z + bb.z) + (cq.z + dq.z)) * inv);
    dst[3] = (_Float16)(((a.w + bb.w) + (cq.w + dq.w)) * inv);
  }
}

// Launch 2: MFMA head. Grid 512 x 64 thr; wave = one 16x16 tile (eg, nt).
// bid = nt*64 + eg  =>  bid % 8 == eg % 8: all 8 nt-blocks of an eg land on
// the SAME XCD (round-robin dispatch) -> A-panel HBM-fetched once per eg.
// 4-pair ILP: 8 loads in flight. Epilogue: +b1, relu, *W2, butterfly -> ts.
__global__ __launch_bounds__(64) void head_mfma(
    const _Float16* __restrict__ gs, const _Float16* __restrict__ w1s,
    const float* __restrict__ b1, const float* __restrict__ W2,
    float* __restrict__ ts) {
  const int l  = threadIdx.x;
  const int eg = blockIdx.x & 63;
  const int nt = blockIdx.x >> 6;

  const half8* Ap = reinterpret_cast<const half8*>(gs) + (size_t)eg * NK * 64 + l;
  const half8* Bp = reinterpret_cast<const half8*>(w1s) + (size_t)nt * NK * 64 + l;

  floatx4 acc0 = {0.f, 0.f, 0.f, 0.f};
  floatx4 acc1 = {0.f, 0.f, 0.f, 0.f};
  #pragma unroll 2
  for (int kk = 0; kk < NK; kk += 4) {   // 12 iters, 8 loads in flight each
    half8 a0 = Ap[(size_t)(kk + 0) * 64];
    half8 b0 = Bp[(size_t)(kk + 0) * 64];
    half8 a1 = Ap[(size_t)(kk + 1) * 64];
    half8 b1v = Bp[(size_t)(kk + 1) * 64];
    half8 a2 = Ap[(size_t)(kk + 2) * 64];
    half8 b2v = Bp[(size_t)(kk + 2) * 64];
    half8 a3 = Ap[(size_t)(kk + 3) * 64];
    half8 b3v = Bp[(size_t)(kk + 3) * 64];
    acc0 = __builtin_amdgcn_mfma_f32_16x16x32_f16(a0, b0, acc0, 0, 0, 0);
    acc1 = __builtin_amdgcn_mfma_f32_16x16x32_f16(a1, b1v, acc1, 0, 0, 0);
    acc0 = __builtin_amdgcn_mfma_f32_16x16x32_f16(a2, b2v, acc0, 0, 0, 0);
    acc1 = __builtin_amdgcn_mfma_f32_16x16x32_f16(a3, b3v, acc1, 0, 0, 0);
  }

  // C/D: col = l&15 (n-local), row = (l>>4)*4 + r (example-local). [m89]
  const int col = l & 15;
  const int n = nt * 16 + col;
  const float b1n = b1[n];
  const float w2n = W2[n];
  #pragma unroll
  for (int r = 0; r < 4; ++r) {
    float h = fmaxf((acc0[r] + acc1[r]) + b1n, 0.f) * w2n;
    h += __shfl_xor(h, 1);
    h += __shfl_xor(h, 2);
    h += __shfl_xor(h, 4);
    h += __shfl_xor(h, 8);
    if (col == 0) {
      const int m = (l >> 4) * 4 + r;
      ts[(size_t)(eg * 16 + m) * 8 + nt] = h;
    }
  }
}

// Launch 3 (R21-exact): out[e] = sigmoid(b2 + sum_nt ts[e][nt]).
__global__ __launch_bounds__(256) void fin(
    const float* __restrict__ ts, const float* __restrict__ b2,
    float* __restrict__ out) {
  const int e = blockIdx.x * 256 + threadIdx.x;
  const float4* p = reinterpret_cast<const float4*>(ts + (size_t)e * 8);
  float4 u = p[0], v = p[1];
  float s = ((u.x + u.y) + (u.z + u.w)) + ((v.x + v.y) + (v.z + v.w)) + b2[0];
  out[e] = 1.0f / (1.0f + expf(-s));
}

extern "C" void kernel_launch(void* const* d_in, const int* in_sizes, int n_in,
                              void* d_out, int out_size, void* d_ws, size_t ws_size,
                              hipStream_t stream) {
  const float* feat = (const float*)d_in[0];   // [B,S,H] fp32
  const int* start  = (const int*)d_in[1];     // [B]
  const int* endp   = (const int*)d_in[2];     // [B]
  const float* W1   = (const float*)d_in[3];   // [2H,D1]
  const float* b1   = (const float*)d_in[4];   // [D1]
  const float* W2   = (const float*)d_in[5];   // [D1,1]
  const float* b2   = (const float*)d_in[6];   // [1]
  float* out = (float*)d_out;                  // [B]

  _Float16* gs  = (_Float16*)d_ws;             // [64][48][64][8]
  _Float16* w1s = gs + (size_t)Bn * K2;        // [8][48][64][8]
  float* ts     = (float*)(w1s + (size_t)D1 * K2);  // [1024][8]

  hipLaunchKernelGGL(pool_cast, dim3(NCAST + Bn), dim3(256), 0, stream,
                     feat, start, endp, W1, gs, w1s);
  hipLaunchKernelGGL(head_mfma, dim3(512), dim3(64), 0, stream,
                     gs, w1s, b1, W2, ts);
  hipLaunchKernelGGL(fin, dim3(Bn / 256), dim3(256), 0, stream,
                     ts, b2, out);
}

// Round 23
// 31.943 us; speedup vs baseline: 176.0735x; 1.0551x over previous
//
#include <hip/hip_runtime.h>
#include <math.h>

// Problem constants (from reference):
constexpr int Bn = 1024;
constexpr int S  = 512;
constexpr int H  = 768;
constexpr int D1 = 128;
constexpr int HV = H / 4;     // 192 float4 per feature row
constexpr int K2 = 2 * H;     // 1536
constexpr int NK = K2 / 32;   // 48 K-steps total
constexpr int NKH = NK / 2;   // 24 K-steps per k-half
constexpr int NCAST = 16;     // W1 cast blocks (first in launch-1 grid)

typedef _Float16 half8 __attribute__((ext_vector_type(8)));
typedef _Float16 half4v __attribute__((ext_vector_type(4)));
typedef float floatx4 __attribute__((ext_vector_type(4)));

// ws layout:
//   g16 [1024][1536] f16 — concat [cls | span-mean], LINEAR (3 MB)
//   w1s [8][48][64][8] f16 — W1^T in MFMA fragment order (384 KB)
//   p0, p1 [1024][128] f32 — raw k-half GEMM partials (512 KB each)
//
// B fragment order: element (lane=lg*16+ni, e) of k-tile kk holds
// k = kk*32 + lg*8 + e. A uses the SAME (lane,e)->k map via linear gathers,
// so any internal MFMA k-permutation cancels (validated R20-22, absmax 3.9e-3).

__device__ __forceinline__ size_t swz_off(int tile, int kk, int lg, int idx) {
  return ((((size_t)tile * NK + kk) * 64) + lg * 16 + idx) * 8;
}

// Launch 1: blocks [0,NCAST): cast W1 -> w1s; [NCAST,+1024): R20-exact pool
// (R16 pool body + coalesced LINEAR f16 writes of cls row and span mean).
__global__ __launch_bounds__(256) void pool_cast(
    const float* __restrict__ feat, const int* __restrict__ start,
    const int* __restrict__ endp, const float* __restrict__ W1,
    _Float16* __restrict__ g16, _Float16* __restrict__ w1s) {
  __shared__ float4 pacc[4][3][64];   // 12 KB (pool path only)
  const int t = threadIdx.x;

  if (blockIdx.x < NCAST) {
    // ---- cast W1[1536][128] -> w1s (B fragment order; small, once) ----
    const int c  = blockIdx.x;
    const int n  = t & 127;
    const int sb = t >> 7;            // 0/1
    const int nt = n >> 4, ni = n & 15;
    #pragma unroll
    for (int j = 0; j < 6; ++j) {
      const int k0 = c * 96 + sb * 48 + j * 8;   // 8-aligned
      _Float16 h[8];
      #pragma unroll
      for (int i = 0; i < 8; ++i) {
        h[i] = (_Float16)W1[(size_t)(k0 + i) * D1 + n];  // coalesced per row
      }
      const int kk = k0 >> 5, lg = (k0 >> 3) & 3;
      *reinterpret_cast<half8*>(w1s + swz_off(nt, kk, lg, ni)) =
          *reinterpret_cast<half8*>(h);
    }
    return;
  }

  // ---- pool (R16-exact) + LINEAR f16 writes ----
  const int b = blockIdx.x - NCAST;
  const int w = t >> 6;
  const int l = t & 63;
  const float4* base =
      reinterpret_cast<const float4*>(feat) + (size_t)b * (S * HV);

  // CLS row -> g16[b][0..768) (coalesced 8B/thread)
  if (t < 192) {
    float4 cv = base[t];              // row 0, col t
    half4v hc;
    hc.x = (_Float16)cv.x; hc.y = (_Float16)cv.y;
    hc.z = (_Float16)cv.z; hc.w = (_Float16)cv.w;
    *reinterpret_cast<half4v*>(g16 + (size_t)b * K2 + t * 4) = hc;
  }

  const int s0 = start[b];
  const int s1 = endp[b];

  float4 c0{0,0,0,0}, c1{0,0,0,0}, c2{0,0,0,0};
  float4 d0{0,0,0,0}, d1{0,0,0,0}, d2{0,0,0,0};
  int s = s0 + w;
  for (; s + 4 < s1; s += 8) {
    const float4* r0 = base + (size_t)s * HV;
    const float4* r1 = base + (size_t)(s + 4) * HV;
    float4 u0 = r0[l], u1 = r0[l + 64], u2 = r0[l + 128];
    float4 v0 = r1[l], v1 = r1[l + 64], v2 = r1[l + 128];
    c0.x += u0.x; c0.y += u0.y; c0.z += u0.z; c0.w += u0.w;
    c1.x += u1.x; c1.y += u1.y; c1.z += u1.z; c1.w += u1.w;
    c2.x += u2.x; c2.y += u2.y; c2.z += u2.z; c2.w += u2.w;
    d0.x += v0.x; d0.y += v0.y; d0.z += v0.z; d0.w += v0.w;
    d1.x += v1.x; d1.y += v1.y; d1.z += v1.z; d1.w += v1.w;
    d2.x += v2.x; d2.y += v2.y; d2.z += v2.z; d2.w += v2.w;
  }
  for (; s < s1; s += 4) {
    const float4* r0 = base + (size_t)s * HV;
    float4 u0 = r0[l], u1 = r0[l + 64], u2 = r0[l + 128];
    c0.x += u0.x; c0.y += u0.y; c0.z += u0.z; c0.w += u0.w;
    c1.x += u1.x; c1.y += u1.y; c1.z += u1.z; c1.w += u1.w;
    c2.x += u2.x; c2.y += u2.y; c2.z += u2.z; c2.w += u2.w;
  }
  c0.x += d0.x; c0.y += d0.y; c0.z += d0.z; c0.w += d0.w;
  c1.x += d1.x; c1.y += d1.y; c1.z += d1.z; c1.w += d1.w;
  c2.x += d2.x; c2.y += d2.y; c2.z += d2.z; c2.w += d2.w;
  pacc[w][0][l] = c0;
  pacc[w][1][l] = c1;
  pacc[w][2][l] = c2;
  __syncthreads();

  if (t < 192) {
    const int seg = t >> 6, ln = t & 63;
    float4 a = pacc[0][seg][ln], bb = pacc[1][seg][ln];
    float4 cq = pacc[2][seg][ln], dq = pacc[3][seg][ln];
    const float inv = 1.0f / (float)(s1 - s0);
    half4v r;
    r.x = (_Float16)(((a.x + bb.x) + (cq.x + dq.x)) * inv);
    r.y = (_Float16)(((a.y + bb.y) + (cq.y + dq.y)) * inv);
    r.z = (_Float16)(((a.z + bb.z) + (cq.z + dq.z)) * inv);
    r.w = (_Float16)(((a.w + bb.w) + (cq.w + dq.w)) * inv);
    *reinterpret_cast<half4v*>(g16 + (size_t)b * K2 + H + t * 4) = r;
  }
}

// Launch 2: MFMA head, K-split. Grid 1024 x 64 thr; wave = (eg, nt, khalf).
// bid = ((nt*2+kh)*64 + eg) => bid%8 == eg%8: one XCD per eg's A-panel.
// A gathered from LINEAR g16 (16 rows x 64B per load-group); B contiguous.
// Raw f32 tile partials to plane[kh] (relu can't fuse across the K-split).
__global__ __launch_bounds__(64) void head_mfma(
    const _Float16* __restrict__ g16, const _Float16* __restrict__ w1s,
    float* __restrict__ p0, float* __restrict__ p1) {
  const int l  = threadIdx.x;
  const int eg = blockIdx.x & 63;
  const int rest = blockIdx.x >> 6;   // 0..15
  const int nt = rest >> 1;
  const int kh = rest & 1;

  const int lg = l >> 4, li = l & 15;
  const int e0 = eg * 16;

  // A: g16[e0+li][kh*768 + kk*32 + lg*8 + 0..7]
  const _Float16* Abase = g16 + (size_t)(e0 + li) * K2 + kh * (K2 / 2) + lg * 8;
  // B: fragment order, global k-tile index kh*24+kk
  const half8* Bp = reinterpret_cast<const half8*>(w1s) +
                    ((size_t)nt * NK + kh * NKH) * 64 + l;

  floatx4 acc0 = {0.f, 0.f, 0.f, 0.f};
  floatx4 acc1 = {0.f, 0.f, 0.f, 0.f};
  #pragma unroll 2
  for (int kk = 0; kk < NKH; kk += 4) {  // 6 iters, 8 loads in flight
    half8 a0 = *reinterpret_cast<const half8*>(Abase + (kk + 0) * 32);
    half8 b0 = Bp[(size_t)(kk + 0) * 64];
    half8 a1 = *reinterpret_cast<const half8*>(Abase + (kk + 1) * 32);
    half8 b1v = Bp[(size_t)(kk + 1) * 64];
    half8 a2 = *reinterpret_cast<const half8*>(Abase + (kk + 2) * 32);
    half8 b2v = Bp[(size_t)(kk + 2) * 64];
    half8 a3 = *reinterpret_cast<const half8*>(Abase + (kk + 3) * 32);
    half8 b3v = Bp[(size_t)(kk + 3) * 64];
    acc0 = __builtin_amdgcn_mfma_f32_16x16x32_f16(a0, b0, acc0, 0, 0, 0);
    acc1 = __builtin_amdgcn_mfma_f32_16x16x32_f16(a1, b1v, acc1, 0, 0, 0);
    acc0 = __builtin_amdgcn_mfma_f32_16x16x32_f16(a2, b2v, acc0, 0, 0, 0);
    acc1 = __builtin_amdgcn_mfma_f32_16x16x32_f16(a3, b3v, acc1, 0, 0, 0);
  }

  // C/D: col = l&15 (n-local), row = lg*4 + r (example-local). [m89]
  float* plane = kh ? p1 : p0;
  const int n = nt * 16 + li;
  #pragma unroll
  for (int r = 0; r < 4; ++r) {
    const int m = lg * 4 + r;
    plane[(size_t)(e0 + m) * D1 + n] = acc0[r] + acc1[r];
  }
}

// Launch 3 (R16-finalize shape): wave per example; lane l owns k-pair.
// h = b1 + p0 + p1; relu; *W2; butterfly; sigmoid.
__global__ __launch_bounds__(256) void fin(
    const float* __restrict__ p0, const float* __restrict__ p1,
    const float* __restrict__ b1, const float* __restrict__ W2,
    const float* __restrict__ b2, float* __restrict__ out) {
  const int t = threadIdx.x;
  const int w = t >> 6, l = t & 63;
  const int e = blockIdx.x * 4 + w;
  const int k0 = l, k1 = l + 64;
  const size_t base = (size_t)e * D1;
  float h0 = b1[k0] + p0[base + k0] + p1[base + k0];
  float h1 = b1[k1] + p0[base + k1] + p1[base + k1];
  h0 = fmaxf(h0, 0.f); h1 = fmaxf(h1, 0.f);
  float v = h0 * W2[k0] + h1 * W2[k1];
  #pragma unroll
  for (int off = 32; off > 0; off >>= 1) v += __shfl_down(v, off);
  if (l == 0) out[e] = 1.0f / (1.0f + expf(-(v + b2[0])));
}

extern "C" void kernel_launch(void* const* d_in, const int* in_sizes, int n_in,
                              void* d_out, int out_size, void* d_ws, size_t ws_size,
                              hipStream_t stream) {
  const float* feat = (const float*)d_in[0];   // [B,S,H] fp32
  const int* start  = (const int*)d_in[1];     // [B]
  const int* endp   = (const int*)d_in[2];     // [B]
  const float* W1   = (const float*)d_in[3];   // [2H,D1]
  const float* b1   = (const float*)d_in[4];   // [D1]
  const float* W2   = (const float*)d_in[5];   // [D1,1]
  const float* b2   = (const float*)d_in[6];   // [1]
  float* out = (float*)d_out;                  // [B]

  _Float16* g16 = (_Float16*)d_ws;             // [1024][1536]
  _Float16* w1s = g16 + (size_t)Bn * K2;       // [8][48][64][8]
  float* p0     = (float*)(w1s + (size_t)D1 * K2);  // [1024][128]
  float* p1     = p0 + (size_t)Bn * D1;             // [1024][128]

  hipLaunchKernelGGL(pool_cast, dim3(NCAST + Bn), dim3(256), 0, stream,
                     feat, start, endp, W1, g16, w1s);
  hipLaunchKernelGGL(head_mfma, dim3(1024), dim3(64), 0, stream,
                     g16, w1s, p0, p1);
  hipLaunchKernelGGL(fin, dim3(Bn / 4), dim3(256), 0, stream,
                     p0, p1, b1, W2, b2, out);
}

// Round 24
// 30.627 us; speedup vs baseline: 183.6371x; 1.0430x over previous
//
#include <hip/hip_runtime.h>
#include <math.h>

// Problem constants (from reference):
constexpr int Bn = 1024;
constexpr int S  = 512;
constexpr int H  = 768;
constexpr int D1 = 128;
constexpr int HV = H / 4;     // 192 float4 per feature row
constexpr int K2 = 2 * H;     // 1536
constexpr int NK = K2 / 32;   // 48 K-tiles total
constexpr int NKH = 24;       // K-tiles per half
constexpr int NCAST = 8;      // W1 cast blocks (CRC half only)
constexpr int NCLS = 128;     // cls-head blocks (4 waves each = 512 tiles)

typedef _Float16 half8 __attribute__((ext_vector_type(8)));
typedef _Float16 half4v __attribute__((ext_vector_type(4)));
typedef float floatx4 __attribute__((ext_vector_type(4)));

// ws layout:
//   gcrc [1024][768] f16 — span means, LINEAR (1.5 MB)
//   w1s  [8][48][64][8] f16 — W1^T fragment order (only tiles 24..47 filled)
//   p0,p1,p2 [1024][128] f32 — raw GEMM partials (kh0, crc-q0, crc-q1)
//
// Fragment map: element (lane=lg*16+idx, e) of k-tile kk holds k = kk*32 +
// lg*8 + e. A and B use the SAME map, so any internal MFMA k-permutation
// cancels (validated R20-23, absmax 3.9e-3 = f16 rounding).

__device__ __forceinline__ size_t swz_off(int tile, int kk, int lg, int idx) {
  return ((((size_t)tile * NK + kk) * 64) + lg * 16 + idx) * 8;
}

// Launch 1: [0,NCAST) cast W1 CRC half; [NCAST,+NCLS) cls-half head
// (self-cast from feat row 0 + W1 — no staging dependency); rest: pool.
__global__ __launch_bounds__(256) void launch1(
    const float* __restrict__ feat, const int* __restrict__ start,
    const int* __restrict__ endp, const float* __restrict__ W1,
    _Float16* __restrict__ gcrc, _Float16* __restrict__ w1s,
    float* __restrict__ p0) {
  __shared__ float4 pacc[4][3][64];   // 12 KB (pool path only)
  const int t = threadIdx.x;

  if (blockIdx.x < NCAST) {
    // ---- cast W1[768..1536)[128] -> w1s tiles 24..47 ----
    const int c  = blockIdx.x + 8;    // 96-row chunk index 8..15
    const int n  = t & 127;
    const int sb = t >> 7;            // 0/1
    const int nt = n >> 4, ni = n & 15;
    #pragma unroll
    for (int j = 0; j < 6; ++j) {
      const int k0 = c * 96 + sb * 48 + j * 8;   // 8-aligned, >= 768
      _Float16 h[8];
      #pragma unroll
      for (int i = 0; i < 8; ++i) {
        h[i] = (_Float16)W1[(size_t)(k0 + i) * D1 + n];  // coalesced per row
      }
      const int kk = k0 >> 5, lg = (k0 >> 3) & 3;
      *reinterpret_cast<half8*>(w1s + swz_off(nt, kk, lg, ni)) =
          *reinterpret_cast<half8*>(h);
    }
    return;
  }

  if (blockIdx.x < NCAST + NCLS) {
    // ---- CLS-half head (kh=0): wave = one 16x16 tile (eg, nt) ----
    const int w = t >> 6, l = t & 63;
    const int tid = (blockIdx.x - NCAST) * 4 + w;   // 0..511
    const int eg = tid & 63;
    const int nt = tid >> 6;
    const int lg = l >> 4, li = l & 15;
    const int e0 = eg * 16;
    const int n = nt * 16 + li;

    const float* arow = feat + (size_t)(e0 + li) * S * H;  // CLS row
    const float* wcol = W1 + n;

    floatx4 acc0 = {0.f, 0.f, 0.f, 0.f};
    floatx4 acc1 = {0.f, 0.f, 0.f, 0.f};
    #pragma unroll 2
    for (int kk = 0; kk < NKH; kk += 2) {
      #define MKFRAG(kkq, accq)                                            \
      {                                                                    \
        const int kb = (kkq) * 32 + lg * 8;                                \
        float4 fa = *reinterpret_cast<const float4*>(arow + kb);           \
        float4 fb = *reinterpret_cast<const float4*>(arow + kb + 4);       \
        const float* wb = wcol + (size_t)kb * D1;                          \
        float w0 = wb[0 * D1], w1v = wb[1 * D1], w2v = wb[2 * D1];         \
        float w3v = wb[3 * D1], w4v = wb[4 * D1], w5v = wb[5 * D1];        \
        float w6v = wb[6 * D1], w7v = wb[7 * D1];                          \
        half8 av, bv;                                                      \
        av[0] = (_Float16)fa.x; av[1] = (_Float16)fa.y;                    \
        av[2] = (_Float16)fa.z; av[3] = (_Float16)fa.w;                    \
        av[4] = (_Float16)fb.x; av[5] = (_Float16)fb.y;                    \
        av[6] = (_Float16)fb.z; av[7] = (_Float16)fb.w;                    \
        bv[0] = (_Float16)w0;  bv[1] = (_Float16)w1v;                      \
        bv[2] = (_Float16)w2v; bv[3] = (_Float16)w3v;                      \
        bv[4] = (_Float16)w4v; bv[5] = (_Float16)w5v;                      \
        bv[6] = (_Float16)w6v; bv[7] = (_Float16)w7v;                      \
        accq = __builtin_amdgcn_mfma_f32_16x16x32_f16(av, bv, accq, 0, 0, 0); \
      }
      MKFRAG(kk, acc0)
      MKFRAG(kk + 1, acc1)
      #undef MKFRAG
    }
    // C/D: col = li (n-local), row = lg*4 + r (example-local). [m89]
    #pragma unroll
    for (int r = 0; r < 4; ++r) {
      p0[(size_t)(e0 + lg * 4 + r) * D1 + n] = acc0[r] + acc1[r];
    }
    return;
  }

  // ---- pool (R23-exact body), writes CRC mean only -> gcrc linear ----
  const int b = blockIdx.x - (NCAST + NCLS);
  const int w = t >> 6;
  const int l = t & 63;
  const float4* base =
      reinterpret_cast<const float4*>(feat) + (size_t)b * (S * HV);

  const int s0 = start[b];
  const int s1 = endp[b];

  float4 c0{0,0,0,0}, c1{0,0,0,0}, c2{0,0,0,0};
  float4 d0{0,0,0,0}, d1{0,0,0,0}, d2{0,0,0,0};
  int s = s0 + w;
  for (; s + 4 < s1; s += 8) {
    const float4* r0 = base + (size_t)s * HV;
    const float4* r1 = base + (size_t)(s + 4) * HV;
    float4 u0 = r0[l], u1 = r0[l + 64], u2 = r0[l + 128];
    float4 v0 = r1[l], v1 = r1[l + 64], v2 = r1[l + 128];
    c0.x += u0.x; c0.y += u0.y; c0.z += u0.z; c0.w += u0.w;
    c1.x += u1.x; c1.y += u1.y; c1.z += u1.z; c1.w += u1.w;
    c2.x += u2.x; c2.y += u2.y; c2.z += u2.z; c2.w += u2.w;
    d0.x += v0.x; d0.y += v0.y; d0.z += v0.z; d0.w += v0.w;
    d1.x += v1.x; d1.y += v1.y; d1.z += v1.z; d1.w += v1.w;
    d2.x += v2.x; d2.y += v2.y; d2.z += v2.z; d2.w += v2.w;
  }
  for (; s < s1; s += 4) {
    const float4* r0 = base + (size_t)s * HV;
    float4 u0 = r0[l], u1 = r0[l + 64], u2 = r0[l + 128];
    c0.x += u0.x; c0.y += u0.y; c0.z += u0.z; c0.w += u0.w;
    c1.x += u1.x; c1.y += u1.y; c1.z += u1.z; c1.w += u1.w;
    c2.x += u2.x; c2.y += u2.y; c2.z += u2.z; c2.w += u2.w;
  }
  c0.x += d0.x; c0.y += d0.y; c0.z += d0.z; c0.w += d0.w;
  c1.x += d1.x; c1.y += d1.y; c1.z += d1.z; c1.w += d1.w;
  c2.x += d2.x; c2.y += d2.y; c2.z += d2.z; c2.w += d2.w;
  pacc[w][0][l] = c0;
  pacc[w][1][l] = c1;
  pacc[w][2][l] = c2;
  __syncthreads();

  if (t < 192) {
    const int seg = t >> 6, ln = t & 63;
    float4 a = pacc[0][seg][ln], bb = pacc[1][seg][ln];
    float4 cq = pacc[2][seg][ln], dq = pacc[3][seg][ln];
    const float inv = 1.0f / (float)(s1 - s0);
    half4v r;
    r.x = (_Float16)(((a.x + bb.x) + (cq.x + dq.x)) * inv);
    r.y = (_Float16)(((a.y + bb.y) + (cq.y + dq.y)) * inv);
    r.z = (_Float16)(((a.z + bb.z) + (cq.z + dq.z)) * inv);
    r.w = (_Float16)(((a.w + bb.w) + (cq.w + dq.w)) * inv);
    *reinterpret_cast<half4v*>(gcrc + (size_t)b * H + t * 4) = r;
  }
}

// Launch 2: CRC head, k-quarter split. Grid 1024 x 64; wave = (eg, nt, kq).
// bid = ((nt*2+kq)*64 + eg) => bid%8 == eg%8 (XCD locality on gcrc panel).
__global__ __launch_bounds__(64) void crc_mfma(
    const _Float16* __restrict__ gcrc, const _Float16* __restrict__ w1s,
    float* __restrict__ p1, float* __restrict__ p2) {
  const int l  = threadIdx.x;
  const int eg = blockIdx.x & 63;
  const int rest = blockIdx.x >> 6;   // 0..15
  const int nt = rest >> 1;
  const int kq = rest & 1;

  const int lg = l >> 4, li = l & 15;
  const int e0 = eg * 16;

  // A: gcrc[e0+li][(kq*12+kk)*32 + lg*8 + 0..7]
  const _Float16* Abase = gcrc + (size_t)(e0 + li) * H + kq * 384 + lg * 8;
  // B: fragment order, global k-tile = 24 + kq*12 + kk
  const half8* Bp = reinterpret_cast<const half8*>(w1s) +
                    ((size_t)nt * NK + NKH + kq * 12) * 64 + l;

  floatx4 acc0 = {0.f, 0.f, 0.f, 0.f};
  floatx4 acc1 = {0.f, 0.f, 0.f, 0.f};
  #pragma unroll 3
  for (int kk = 0; kk < 12; kk += 4) {  // 3 iters, 8 loads in flight
    half8 a0 = *reinterpret_cast<const half8*>(Abase + (kk + 0) * 32);
    half8 b0 = Bp[(size_t)(kk + 0) * 64];
    half8 a1 = *reinterpret_cast<const half8*>(Abase + (kk + 1) * 32);
    half8 b1v = Bp[(size_t)(kk + 1) * 64];
    half8 a2 = *reinterpret_cast<const half8*>(Abase + (kk + 2) * 32);
    half8 b2v = Bp[(size_t)(kk + 2) * 64];
    half8 a3 = *reinterpret_cast<const half8*>(Abase + (kk + 3) * 32);
    half8 b3v = Bp[(size_t)(kk + 3) * 64];
    acc0 = __builtin_amdgcn_mfma_f32_16x16x32_f16(a0, b0, acc0, 0, 0, 0);
    acc1 = __builtin_amdgcn_mfma_f32_16x16x32_f16(a1, b1v, acc1, 0, 0, 0);
    acc0 = __builtin_amdgcn_mfma_f32_16x16x32_f16(a2, b2v, acc0, 0, 0, 0);
    acc1 = __builtin_amdgcn_mfma_f32_16x16x32_f16(a3, b3v, acc1, 0, 0, 0);
  }

  float* plane = kq ? p2 : p1;
  const int n = nt * 16 + li;
  #pragma unroll
  for (int r = 0; r < 4; ++r) {
    plane[(size_t)(e0 + lg * 4 + r) * D1 + n] = acc0[r] + acc1[r];
  }
}

// Launch 3: fin — wave per example; lane owns k-pair; 3 partial planes.
__global__ __launch_bounds__(256) void fin(
    const float* __restrict__ p0, const float* __restrict__ p1,
    const float* __restrict__ p2, const float* __restrict__ b1,
    const float* __restrict__ W2, const float* __restrict__ b2,
    float* __restrict__ out) {
  const int t = threadIdx.x;
  const int w = t >> 6, l = t & 63;
  const int e = blockIdx.x * 4 + w;
  const int k0 = l, k1 = l + 64;
  const size_t base = (size_t)e * D1;
  float h0 = b1[k0] + p0[base + k0] + p1[base + k0] + p2[base + k0];
  float h1 = b1[k1] + p0[base + k1] + p1[base + k1] + p2[base + k1];
  h0 = fmaxf(h0, 0.f); h1 = fmaxf(h1, 0.f);
  float v = h0 * W2[k0] + h1 * W2[k1];
  #pragma unroll
  for (int off = 32; off > 0; off >>= 1) v += __shfl_down(v, off);
  if (l == 0) out[e] = 1.0f / (1.0f + expf(-(v + b2[0])));
}

extern "C" void kernel_launch(void* const* d_in, const int* in_sizes, int n_in,
                              void* d_out, int out_size, void* d_ws, size_t ws_size,
                              hipStream_t stream) {
  const float* feat = (const float*)d_in[0];   // [B,S,H] fp32
  const int* start  = (const int*)d_in[1];     // [B]
  const int* endp   = (const int*)d_in[2];     // [B]
  const float* W1   = (const float*)d_in[3];   // [2H,D1]
  const float* b1   = (const float*)d_in[4];   // [D1]
  const float* W2   = (const float*)d_in[5];   // [D1,1]
  const float* b2   = (const float*)d_in[6];   // [1]
  float* out = (float*)d_out;                  // [B]

  _Float16* gcrc = (_Float16*)d_ws;            // [1024][768]
  _Float16* w1s  = gcrc + (size_t)Bn * H;      // [8][48][64][8]
  float* p0 = (float*)(w1s + (size_t)D1 * K2); // [1024][128]
  float* p1 = p0 + (size_t)Bn * D1;
  float* p2 = p1 + (size_t)Bn * D1;

  hipLaunchKernelGGL(launch1, dim3(NCAST + NCLS + Bn), dim3(256), 0, stream,
                     feat, start, endp, W1, gcrc, w1s, p0);
  hipLaunchKernelGGL(crc_mfma, dim3(1024), dim3(64), 0, stream,
                     gcrc, w1s, p1, p2);
  hipLaunchKernelGGL(fin, dim3(Bn / 4), dim3(256), 0, stream,
                     p0, p1, p2, b1, W2, b2, out);
}